// Round 1
// baseline (165.613 us; speedup 1.0000x reference)
//
#include <hip/hip_runtime.h>

namespace {
constexpr int kB   = 1000;
constexpr int kT   = 20000;
constexpr int kKt  = 181;
constexpr int kInW = kT + kKt - 1;            // 20180
constexpr int BM   = 16;                      // batch rows per block
constexpr int BT   = 512;                     // output cols per chunk
constexpr int NCH  = 2;                       // chunks per block (prefetch pipeline depth 2)
constexpr int SLAB = BT * NCH;                // 1024 output cols per block
constexpr int NCHUNK = 7;                     // 7 k-chunks of 32 -> k in [0,224) >= 15+181
constexpr int COLS = 768;                     // staged cols per chunk (>=720 needed; 768 -> uniform 12 f4/thread)
constexpr int LDS_STRIDE = COLS + 8;          // 776 shorts = 388 dw; 388%32==4 -> b128 reads conflict-free
constexpr int NPRE = 12;                      // float4 per thread per chunk (16 thr/row * 12 * 4 = 768 cols)

typedef short bf16x8 __attribute__((ext_vector_type(8)));
typedef float f32x4  __attribute__((ext_vector_type(4)));

__device__ __forceinline__ short f32_bf16(float f) {
  union { float f; unsigned u; } x; x.f = f;
  unsigned r = x.u + (0x7fffu + ((x.u >> 16) & 1u));  // RNE
  return (short)(r >> 16);
}
} // namespace

__global__ __launch_bounds__(256, 4)
void biexp_conv_mfma(const float* __restrict__ u, const float* __restrict__ kern,
                     float* __restrict__ out) {
  __shared__ short lds_u[BM * LDS_STRIDE];
  __shared__ float lds_k[kKt];

  const int tid  = threadIdx.x;
  const int lane = tid & 63;
  const int wave = tid >> 6;
  const int quad = lane >> 4;
  const int nn   = lane & 15;
  const int b0    = blockIdx.y * BM;
  const int slab0 = blockIdx.x * SLAB;

  if (tid < kKt) lds_k[tid] = kern[tid];

  // ---- staging geometry: fixed row per thread, 12 float4 at base + 256B*i (imm-foldable)
  const int rl = tid >> 4;                  // 0..15 row within tile
  const int c0 = (tid & 15) * 4;            // float col offset; +64 per i
  int grow = b0 + rl; grow = grow < kB ? grow : kB - 1;   // clamped rows only feed masked outputs
  const float* rowp = u + (size_t)grow * kInW;
  short* ldsw = &lds_u[rl * LDS_STRIDE + c0];

  float4 pre[NPRE];                         // prefetch registers (static-indexed only)

  auto load_chunk = [&](int tbase) {
    if (tbase + COLS <= kInW) {             // block-uniform scalar branch
      const float* p = rowp + tbase + c0;
      #pragma unroll
      for (int i = 0; i < NPRE; ++i) pre[i] = *(const float4*)(p + 64 * i);
    } else {
      // col%4==0 and kInW%4==0 -> a float4 is either fully in range (exact) or fully
      // OOB (clamped garbage; only feeds outputs with gt>=kT, masked / zero taps).
      #pragma unroll
      for (int i = 0; i < NPRE; ++i) {
        int col = tbase + c0 + 64 * i;
        col = col < (kInW - 4) ? col : (kInW - 4);
        pre[i] = *(const float4*)(rowp + col);
      }
    }
  };
  auto write_chunk = [&]() {
    #pragma unroll
    for (int i = 0; i < NPRE; ++i) {
      short4 s;
      s.x = f32_bf16(pre[i].x); s.y = f32_bf16(pre[i].y);
      s.z = f32_bf16(pre[i].z); s.w = f32_bf16(pre[i].w);
      *(short4*)(ldsw + 64 * i) = s;
    }
  };

  // ---- prologue: stage chunk 0
  load_chunk(slab0);
  write_chunk();
  __syncthreads();

  // ---- prefetch chunk 1 NOW: 12 independent loads in flight under bfrag + compute(0)
  load_chunk(slab0 + BT);

  // ---- B fragments: Toeplitz tap matrix B[k][n] = w(k-n), w(i)=kern[180-i]
  // computed once per block, reused for both chunks
  bf16x8 bfrag[NCHUNK];
  #pragma unroll
  for (int c = 0; c < NCHUNK; ++c) {
    #pragma unroll
    for (int j = 0; j < 8; ++j) {
      int idx = 32 * c + quad * 8 + j - nn;    // k - n
      float v = (idx >= 0 && idx < kKt) ? lds_k[kKt - 1 - idx] : 0.0f;
      bfrag[c][j] = f32_bf16(v);
    }
  }

  const short* arow = &lds_u[nn * LDS_STRIDE + quad * 8];
  const bool edge = (b0 + BM > kB) || (slab0 + SLAB > kT);  // block-uniform

  #pragma unroll
  for (int ch = 0; ch < NCH; ++ch) {
    const int tout = slab0 + ch * BT;
    #pragma unroll 2
    for (int jt = 0; jt < BT / 64; ++jt) {
      const int nt = wave * (BT / 4) + jt * 16;
      f32x4 acc = {0.f, 0.f, 0.f, 0.f};
      #pragma unroll
      for (int c = 0; c < NCHUNK; ++c) {
        bf16x8 a = *(const bf16x8*)(arow + nt + 32 * c);
        acc = __builtin_amdgcn_mfma_f32_16x16x32_bf16(a, bfrag[c], acc, 0, 0, 0);
      }
      const int gt = tout + nt + nn;
      if (!edge) {
        #pragma unroll
        for (int r = 0; r < 4; ++r) {
          // write-once output: nontemporal keeps the 80MB stream out of L3 so input stays cached
          __builtin_nontemporal_store(acc[r], &out[(size_t)(b0 + quad * 4 + r) * kT + gt]);
        }
      } else {
        #pragma unroll
        for (int r = 0; r < 4; ++r) {
          const int gb = b0 + quad * 4 + r;
          if (gb < kB && gt < kT) out[(size_t)gb * kT + gt] = acc[r];
        }
      }
    }
    __syncthreads();                 // all waves done reading LDS chunk ch
    if (ch + 1 < NCH) {
      write_chunk();                 // vmcnt wait for prefetch lands HERE (hidden under compute)
      __syncthreads();               // LDS chunk ch+1 ready
    }
  }
}

extern "C" void kernel_launch(void* const* d_in, const int* in_sizes, int n_in,
                              void* d_out, int out_size, void* d_ws, size_t ws_size,
                              hipStream_t stream) {
  const float* u  = (const float*)d_in[0];
  const float* kn = (const float*)d_in[1];
  float* out = (float*)d_out;
  dim3 grid((kT + SLAB - 1) / SLAB, (kB + BM - 1) / BM);   // 20 x 63
  hipLaunchKernelGGL(biexp_conv_mfma, grid, dim3(256, 1, 1), 0, stream, u, kn, out);
}